// Round 3
// baseline (612.423 us; speedup 1.0000x reference)
//
#include <hip/hip_runtime.h>
#include <hip/hip_bf16.h>

// A=8, B=32768, S=128, AD=16, H=64, NH=4, D=16
#define A_N 8
#define B_N 32768
#define S_N 128
#define AD_N 16

typedef __attribute__((ext_vector_type(8))) short short8;
typedef __attribute__((ext_vector_type(4))) float floatx4;

#define MFMA16(a, b, c) __builtin_amdgcn_mfma_f32_16x16x32_bf16(a, b, c, 0, 0, 0)

__device__ __forceinline__ short f2bf(float f) {
    __hip_bfloat16 h = __float2bfloat16(f);
    return *reinterpret_cast<short*>(&h);
}
__device__ __forceinline__ float bf2f(short s) {
    return __uint_as_float(((unsigned)(unsigned short)s) << 16);
}
__device__ __forceinline__ short8 cvt8(float4 x0, float4 x1) {
    short8 r;
    r[0] = f2bf(x0.x); r[1] = f2bf(x0.y); r[2] = f2bf(x0.z); r[3] = f2bf(x0.w);
    r[4] = f2bf(x1.x); r[5] = f2bf(x1.y); r[6] = f2bf(x1.z); r[7] = f2bf(x1.w);
    return r;
}
// wave-local LDS write->read ordering fence (DS pipe is in-order per wave;
// lgkmcnt(0) guarantees writes retired; "memory" stops compiler reordering)
__device__ __forceinline__ void wait_lgkm() {
    asm volatile("s_waitcnt lgkmcnt(0)" ::: "memory");
}
// cross-wave barrier WITHOUT vmcnt drain: prefetch global loads stay in flight
__device__ __forceinline__ void lds_barrier() {
    asm volatile("s_waitcnt lgkmcnt(0)\ns_barrier" ::: "memory");
}

// ---- weight prep: bf16, transposed to [n][k] so B-fragments are 16B loads ----
// shorts: WeT[64][160]@0 | WsT[64][128]@10240 | WkT[64][64]@18432
//         WselT[64][64]@22528 | WvT[64][64]@26624 | W1T[64][128]@30720
#define W_TOTAL 38912
__global__ void prep_weights(const float* __restrict__ Ws, const float* __restrict__ We,
                             const float* __restrict__ Wk, const float* __restrict__ Wsel,
                             const float* __restrict__ Wv, const float* __restrict__ W1,
                             short* __restrict__ w) {
    int idx = blockIdx.x * 256 + threadIdx.x;
    if (idx >= W_TOTAL) return;
    float v;
    if (idx < 10240)      { int n = idx / 160, k = idx % 160; v = (k < 144) ? We[k * 64 + n] : 0.f; }
    else if (idx < 18432) { int i = idx - 10240; int n = i / 128, k = i % 128; v = Ws[k * 64 + n]; }
    else if (idx < 22528) { int i = idx - 18432; int c = i / 64, h = i % 64; v = Wk[(c >> 4) * 1024 + h * 16 + (c & 15)]; }
    else if (idx < 26624) { int i = idx - 22528; int c = i / 64, h = i % 64; v = Wsel[(c >> 4) * 1024 + h * 16 + (c & 15)]; }
    else if (idx < 30720) { int i = idx - 26624; int c = i / 64, h = i % 64; v = Wv[(c >> 4) * 1024 + h * 16 + (c & 15)]; }
    else                  { int i = idx - 30720; int n = i / 128, k = i % 128; v = W1[k * 64 + n]; }
    w[idx] = f2bf(v);
}

#define ST 72          // LDS row stride (shorts): 144B rows, 16B-aligned, 36 dwords
#define T_TILES 2      // batch-tiles per block; grid = 4096 / T_TILES

__global__ __launch_bounds__(256, 4)
void attention_critic_mfma(
    const float* __restrict__ states, const float* __restrict__ actions,
    const float* __restrict__ bs, const float* __restrict__ be,
    const float* __restrict__ bv, const float* __restrict__ b1,
    const float* __restrict__ W2, const float* __restrict__ b2,
    const short* __restrict__ wts, float* __restrict__ out)
{
    __shared__ short Eb[64 * ST];   // sa_enc
    __shared__ short Tb[64 * ST];   // s_enc -> Sel -> 'other'  (all wave/thread-local reuse)
    __shared__ short Kb[64 * ST];   // keys   (cross-wave in phase 3)
    __shared__ short Vb[64 * ST];   // values (cross-wave in phase 3)

    const int tid  = threadIdx.x;
    const int wv   = tid >> 6;      // wave = M-tile
    const int lane = tid & 63;
    const int lq   = lane >> 4;
    const int ln   = lane & 15;
    const int rA   = wv * 16 + ln;  // A-fragment row for this lane
    const int aA   = rA >> 3, blA = rA & 7;

    const short* WeT   = wts;
    const short* WsT   = wts + 10240;
    const short* WkT   = wts + 18432;
    const short* WselT = wts + 22528;
    const short* WvT   = wts + 26624;
    const short* W1T   = wts + 30720;

    const int bbase = blockIdx.x * (T_TILES * 8);
    const float* srow = states  + ((long)aA * B_N + bbase + blA) * S_N;
    const float* arow = actions + ((long)aA * B_N + bbase + blA) * AD_N;

    const floatx4 z = {0.f, 0.f, 0.f, 0.f};

    // -------- prologue: load tile 0 inputs into registers --------
    float4 ps[8]; float4 pa[2];
    #pragma unroll
    for (int s = 0; s < 4; ++s) {
        ps[2 * s]     = *reinterpret_cast<const float4*>(srow + s * 32 + lq * 8);
        ps[2 * s + 1] = *reinterpret_cast<const float4*>(srow + s * 32 + lq * 8 + 4);
    }
    if (lq < 2) {
        pa[0] = *reinterpret_cast<const float4*>(arow + lq * 8);
        pa[1] = *reinterpret_cast<const float4*>(arow + lq * 8 + 4);
    }

    for (int t = 0; t < T_TILES; ++t) {
        const int b0 = bbase + t * 8;

        // ======== Phase 1: E = relu(X@We+be), Senc = relu(states@Ws+bs) ========
        floatx4 accE[4] = {z, z, z, z};
        floatx4 accS[4] = {z, z, z, z};
        #pragma unroll
        for (int s = 0; s < 4; ++s) {
            const int kk = s * 32 + lq * 8;
            short8 af = cvt8(ps[2 * s], ps[2 * s + 1]);
            #pragma unroll
            for (int nt = 0; nt < 4; ++nt) {
                short8 bE = *reinterpret_cast<const short8*>(WeT + (nt * 16 + ln) * 160 + kk);
                short8 bS = *reinterpret_cast<const short8*>(WsT + (nt * 16 + ln) * 128 + kk);
                accE[nt] = MFMA16(af, bE, accE[nt]);
                accS[nt] = MFMA16(af, bS, accS[nt]);
            }
        }
        {   // k tail 128..159: actions for k<144, zero pad beyond
            const int kk = 128 + lq * 8;
            short8 af = {0, 0, 0, 0, 0, 0, 0, 0};
            if (lq < 2) af = cvt8(pa[0], pa[1]);
            #pragma unroll
            for (int nt = 0; nt < 4; ++nt) {
                short8 bE = *reinterpret_cast<const short8*>(WeT + (nt * 16 + ln) * 160 + kk);
                accE[nt] = MFMA16(af, bE, accE[nt]);
            }
        }

        // -------- prefetch next tile (ps/pa are dead now; vmcnt survives barriers)
        if (t + 1 < T_TILES) {
            srow += 8 * S_N; arow += 8 * AD_N;
            #pragma unroll
            for (int s = 0; s < 4; ++s) {
                ps[2 * s]     = *reinterpret_cast<const float4*>(srow + s * 32 + lq * 8);
                ps[2 * s + 1] = *reinterpret_cast<const float4*>(srow + s * 32 + lq * 8 + 4);
            }
            if (lq < 2) {
                pa[0] = *reinterpret_cast<const float4*>(arow + lq * 8);
                pa[1] = *reinterpret_cast<const float4*>(arow + lq * 8 + 4);
            }
        }

        // phase-1 epilogue (C layout: col=ln-group, row=lq*4+i) — wave-local rows
        #pragma unroll
        for (int nt = 0; nt < 4; ++nt) {
            const int col = nt * 16 + ln;
            const float bE = be[col], bS = bs[col];
            #pragma unroll
            for (int i = 0; i < 4; ++i) {
                const int row = wv * 16 + lq * 4 + i;
                Eb[row * ST + col] = f2bf(fmaxf(accE[nt][i] + bE, 0.f));
                Tb[row * ST + col] = f2bf(fmaxf(accS[nt][i] + bS, 0.f));
            }
        }
        wait_lgkm();   // wave-local: phase 2 reads the rows this wave just wrote

        // ======== Phase 2a: Sel = Senc@Wsel (Tb -> Tb, wave-local) ========
        floatx4 accSel[4] = {z, z, z, z};
        #pragma unroll
        for (int s = 0; s < 2; ++s) {
            short8 af = *reinterpret_cast<const short8*>(Tb + rA * ST + s * 32 + lq * 8);
            #pragma unroll
            for (int nt = 0; nt < 4; ++nt)
                accSel[nt] = MFMA16(af, *reinterpret_cast<const short8*>(WselT + (nt * 16 + ln) * 64 + s * 32 + lq * 8), accSel[nt]);
        }
        // overwrite Senc with Sel: write data depends on all lanes' reads via MFMA
        #pragma unroll
        for (int nt = 0; nt < 4; ++nt)
            #pragma unroll
            for (int i = 0; i < 4; ++i)
                Tb[(wv * 16 + lq * 4 + i) * ST + nt * 16 + ln] = f2bf(accSel[nt][i]);

        // ======== Phase 2b: K = E@Wk ; V = relu(E@Wv+bv) ========
        floatx4 accK[4] = {z, z, z, z}, accV[4] = {z, z, z, z};
        #pragma unroll
        for (int s = 0; s < 2; ++s) {
            short8 af = *reinterpret_cast<const short8*>(Eb + rA * ST + s * 32 + lq * 8);
            #pragma unroll
            for (int nt = 0; nt < 4; ++nt) {
                accK[nt] = MFMA16(af, *reinterpret_cast<const short8*>(WkT + (nt * 16 + ln) * 64 + s * 32 + lq * 8), accK[nt]);
                accV[nt] = MFMA16(af, *reinterpret_cast<const short8*>(WvT + (nt * 16 + ln) * 64 + s * 32 + lq * 8), accV[nt]);
            }
        }
        #pragma unroll
        for (int nt = 0; nt < 4; ++nt) {
            const int col = nt * 16 + ln;
            const float bV = bv[col];
            #pragma unroll
            for (int i = 0; i < 4; ++i) {
                const int row = wv * 16 + lq * 4 + i;
                Kb[row * ST + col] = f2bf(accK[nt][i]);
                Vb[row * ST + col] = f2bf(fmaxf(accV[nt][i] + bV, 0.f));
            }
        }
        lds_barrier();   // sync_A: Kb/Vb are read cross-wave below (no vmcnt drain)

        // ======== Phase 3: exclude-self attention, 1 thread per (row, head) ========
        {
            const int r3 = tid >> 2, hn = tid & 3;      // r3 in this wave's 16-row range
            const int a3 = r3 >> 3, bl3 = r3 & 7;
            const int co = hn * 16;
            float selv[16];
            short8 s0 = *reinterpret_cast<const short8*>(Tb + r3 * ST + co);
            short8 s1 = *reinterpret_cast<const short8*>(Tb + r3 * ST + co + 8);
            #pragma unroll
            for (int d = 0; d < 8; ++d) { selv[d] = bf2f(s0[d]); selv[d + 8] = bf2f(s1[d]); }
            float lg[8];
            #pragma unroll
            for (int j = 0; j < 8; ++j) {
                const int rj = j * 8 + bl3;
                short8 k0 = *reinterpret_cast<const short8*>(Kb + rj * ST + co);
                short8 k1 = *reinterpret_cast<const short8*>(Kb + rj * ST + co + 8);
                float acc = 0.f;
                #pragma unroll
                for (int d = 0; d < 8; ++d) acc += selv[d] * bf2f(k0[d]) + selv[d + 8] * bf2f(k1[d]);
                lg[j] = (j == a3) ? -1e9f : acc * 0.25f;   // 1/sqrt(16)
            }
            float m = lg[0];
            #pragma unroll
            for (int j = 1; j < 8; ++j) m = fmaxf(m, lg[j]);
            float e[8], ssum = 0.f;
            #pragma unroll
            for (int j = 0; j < 8; ++j) { e[j] = __expf(lg[j] - m); ssum += e[j]; }
            const float inv = 1.f / ssum;
            float oth[16];
            #pragma unroll
            for (int d = 0; d < 16; ++d) oth[d] = 0.f;
            #pragma unroll
            for (int j = 0; j < 8; ++j) {
                const float wj = e[j] * inv;
                const int rj = j * 8 + bl3;
                short8 v0 = *reinterpret_cast<const short8*>(Vb + rj * ST + co);
                short8 v1 = *reinterpret_cast<const short8*>(Vb + rj * ST + co + 8);
                #pragma unroll
                for (int d = 0; d < 8; ++d) { oth[d] += wj * bf2f(v0[d]); oth[d + 8] += wj * bf2f(v1[d]); }
            }
            short8 o0, o1;
            #pragma unroll
            for (int d = 0; d < 8; ++d) { o0[d] = f2bf(oth[d]); o1[d] = f2bf(oth[d + 8]); }
            // overwrite own Sel slot with 'other' — unique (row,head) owner, no race
            *reinterpret_cast<short8*>(Tb + r3 * ST + co)     = o0;
            *reinterpret_cast<short8*>(Tb + r3 * ST + co + 8) = o1;
        }
        wait_lgkm();   // wave-local: phase 4 reads rows this wave's threads wrote

        // ======== Phase 4: h = relu([E|other]@W1+b1) ; q = h@W2 + b2 ========
        floatx4 accH[4] = {z, z, z, z};
        #pragma unroll
        for (int s = 0; s < 4; ++s) {
            short8 af = (s < 2)
                ? *reinterpret_cast<const short8*>(Eb + rA * ST + s * 32 + lq * 8)
                : *reinterpret_cast<const short8*>(Tb + rA * ST + (s - 2) * 32 + lq * 8);
            #pragma unroll
            for (int nt = 0; nt < 4; ++nt)
                accH[nt] = MFMA16(af, *reinterpret_cast<const short8*>(W1T + (nt * 16 + ln) * 128 + s * 32 + lq * 8), accH[nt]);
        }
        float p0 = 0.f, p1 = 0.f, p2 = 0.f, p3 = 0.f;
        #pragma unroll
        for (int nt = 0; nt < 4; ++nt) {
            const int col = nt * 16 + ln;
            const float w2v = W2[col], bb = b1[col];
            p0 += fmaxf(accH[nt][0] + bb, 0.f) * w2v;
            p1 += fmaxf(accH[nt][1] + bb, 0.f) * w2v;
            p2 += fmaxf(accH[nt][2] + bb, 0.f) * w2v;
            p3 += fmaxf(accH[nt][3] + bb, 0.f) * w2v;
        }
        #pragma unroll
        for (int mk = 1; mk < 16; mk <<= 1) {
            p0 += __shfl_xor(p0, mk, 64);
            p1 += __shfl_xor(p1, mk, 64);
            p2 += __shfl_xor(p2, mk, 64);
            p3 += __shfl_xor(p3, mk, 64);
        }
        if (ln == 0) {
            const float b2v = b2[0];
            float pr[4] = {p0, p1, p2, p3};
            #pragma unroll
            for (int i = 0; i < 4; ++i) {
                const int r = wv * 16 + lq * 4 + i;
                out[(long)(r >> 3) * B_N + b0 + (r & 7)] = pr[i] + b2v;
            }
        }
        lds_barrier();   // sync_C: Kb/Vb reused by next tile's phase 2b
    }
}

extern "C" void kernel_launch(void* const* d_in, const int* in_sizes, int n_in,
                              void* d_out, int out_size, void* d_ws, size_t ws_size,
                              hipStream_t stream) {
    const float* states  = (const float*)d_in[0];
    const float* actions = (const float*)d_in[1];
    const float* Ws      = (const float*)d_in[2];
    const float* bs      = (const float*)d_in[3];
    const float* We      = (const float*)d_in[4];
    const float* be      = (const float*)d_in[5];
    const float* Wk      = (const float*)d_in[6];
    const float* Wsel    = (const float*)d_in[7];
    const float* Wv      = (const float*)d_in[8];
    const float* bv      = (const float*)d_in[9];
    const float* W1      = (const float*)d_in[10];
    const float* b1      = (const float*)d_in[11];
    const float* W2      = (const float*)d_in[12];
    const float* b2      = (const float*)d_in[13];
    short* wts = (short*)d_ws;
    float* out = (float*)d_out;

    prep_weights<<<(W_TOTAL + 255) / 256, 256, 0, stream>>>(Ws, We, Wk, Wsel, Wv, W1, wts);
    attention_critic_mfma<<<(B_N / 8) / T_TILES, 256, 0, stream>>>(
        states, actions, bs, be, bv, b1, W2, b2, wts, out);
}

// Round 4
// 336.532 us; speedup vs baseline: 1.8198x; 1.8198x over previous
//
#include <hip/hip_runtime.h>
#include <hip/hip_bf16.h>

// A=8, B=32768, S=128, AD=16, H=64, NH=4, D=16
#define A_N 8
#define B_N 32768
#define S_N 128
#define AD_N 16

typedef __attribute__((ext_vector_type(8))) short short8;
typedef __attribute__((ext_vector_type(4))) float floatx4;

#define MFMA16(a, b, c) __builtin_amdgcn_mfma_f32_16x16x32_bf16(a, b, c, 0, 0, 0)

__device__ __forceinline__ short f2bf(float f) {
    __hip_bfloat16 h = __float2bfloat16(f);
    return *reinterpret_cast<short*>(&h);
}
__device__ __forceinline__ float bf2f(short s) {
    return __uint_as_float(((unsigned)(unsigned short)s) << 16);
}
// packed f32x2 -> bf16x2 (v_cvt_pk_bf16_f32 on gfx950)
__device__ __forceinline__ void pk2(short8& r, int i, float a, float b) {
    __hip_bfloat162 p = __float22bfloat162_rn(make_float2(a, b));
    short2 s = *reinterpret_cast<short2*>(&p);
    r[i] = s.x; r[i + 1] = s.y;
}
__device__ __forceinline__ short8 cvt8(float4 x0, float4 x1) {
    short8 r;
    pk2(r, 0, x0.x, x0.y); pk2(r, 2, x0.z, x0.w);
    pk2(r, 4, x1.x, x1.y); pk2(r, 6, x1.z, x1.w);
    return r;
}
// wave-local LDS write->read ordering fence (DS pipe is in-order per wave)
__device__ __forceinline__ void wait_lgkm() {
    asm volatile("s_waitcnt lgkmcnt(0)" ::: "memory");
}
// cross-wave barrier without vmcnt drain
__device__ __forceinline__ void lds_barrier() {
    asm volatile("s_waitcnt lgkmcnt(0)\ns_barrier" ::: "memory");
}

// ---- weight prep: bf16, transposed to [n][k] so B-fragments are 16B loads ----
// shorts: WeT[64][160]@0 | WsT[64][128]@10240 | WkT[64][64]@18432
//         WselT[64][64]@22528 | WvT[64][64]@26624 | W1T[64][128]@30720
#define W_TOTAL 38912
__global__ void prep_weights(const float* __restrict__ Ws, const float* __restrict__ We,
                             const float* __restrict__ Wk, const float* __restrict__ Wsel,
                             const float* __restrict__ Wv, const float* __restrict__ W1,
                             short* __restrict__ w) {
    int idx = blockIdx.x * 256 + threadIdx.x;
    if (idx >= W_TOTAL) return;
    float v;
    if (idx < 10240)      { int n = idx / 160, k = idx % 160; v = (k < 144) ? We[k * 64 + n] : 0.f; }
    else if (idx < 18432) { int i = idx - 10240; int n = i / 128, k = i % 128; v = Ws[k * 64 + n]; }
    else if (idx < 22528) { int i = idx - 18432; int c = i / 64, h = i % 64; v = Wk[(c >> 4) * 1024 + h * 16 + (c & 15)]; }
    else if (idx < 26624) { int i = idx - 22528; int c = i / 64, h = i % 64; v = Wsel[(c >> 4) * 1024 + h * 16 + (c & 15)]; }
    else if (idx < 30720) { int i = idx - 26624; int c = i / 64, h = i % 64; v = Wv[(c >> 4) * 1024 + h * 16 + (c & 15)]; }
    else                  { int i = idx - 30720; int n = i / 128, k = i % 128; v = W1[k * 64 + n]; }
    w[idx] = f2bf(v);
}

#define ST 72   // LDS row stride (shorts): 144B rows, 16B-aligned

__global__ __launch_bounds__(256, 4)
void attention_critic_mfma(
    const float* __restrict__ states, const float* __restrict__ actions,
    const float* __restrict__ bs, const float* __restrict__ be,
    const float* __restrict__ bv, const float* __restrict__ b1,
    const float* __restrict__ W2, const float* __restrict__ b2,
    const short* __restrict__ wts, float* __restrict__ out)
{
    __shared__ short Eb[64 * ST];   // sa_enc
    __shared__ short Tb[64 * ST];   // s_enc -> Sel -> 'other' (wave/thread-local reuse)
    __shared__ short Kb[64 * ST];   // keys   (cross-wave in phase 3)
    __shared__ short Vb[64 * ST];   // values (cross-wave in phase 3)

    const int tid  = threadIdx.x;
    const int wv   = tid >> 6;      // wave = M-tile
    const int lane = tid & 63;
    const int lq   = lane >> 4;
    const int ln   = lane & 15;
    const int rA   = wv * 16 + ln;  // A-fragment row for this lane
    const int aA   = rA >> 3, blA = rA & 7;
    const int b0   = blockIdx.x * 8;

    const short* WeT   = wts;
    const short* WsT   = wts + 10240;
    const short* WkT   = wts + 18432;
    const short* WselT = wts + 22528;
    const short* WvT   = wts + 26624;
    const short* W1T   = wts + 30720;

    const float* srow = states  + ((long)aA * B_N + b0 + blA) * S_N;
    const float* arow = actions + ((long)aA * B_N + b0 + blA) * AD_N;

    const floatx4 z = {0.f, 0.f, 0.f, 0.f};

    // ======== Phase 1: E = relu(X@We+be), Senc = relu(states@Ws+bs) ========
    floatx4 accE[4] = {z, z, z, z};
    floatx4 accS[4] = {z, z, z, z};
    #pragma unroll
    for (int s = 0; s < 4; ++s) {
        const int kk = s * 32 + lq * 8;
        float4 x0 = *reinterpret_cast<const float4*>(srow + kk);
        float4 x1 = *reinterpret_cast<const float4*>(srow + kk + 4);
        short8 af = cvt8(x0, x1);
        #pragma unroll
        for (int nt = 0; nt < 4; ++nt) {
            short8 bE = *reinterpret_cast<const short8*>(WeT + (nt * 16 + ln) * 160 + kk);
            short8 bS = *reinterpret_cast<const short8*>(WsT + (nt * 16 + ln) * 128 + kk);
            accE[nt] = MFMA16(af, bE, accE[nt]);
            accS[nt] = MFMA16(af, bS, accS[nt]);
        }
    }
    {   // k tail 128..159: actions for k<144, zero pad beyond
        const int kk = 128 + lq * 8;
        short8 af = {0, 0, 0, 0, 0, 0, 0, 0};
        if (lq < 2) {
            float4 x0 = *reinterpret_cast<const float4*>(arow + lq * 8);
            float4 x1 = *reinterpret_cast<const float4*>(arow + lq * 8 + 4);
            af = cvt8(x0, x1);
        }
        #pragma unroll
        for (int nt = 0; nt < 4; ++nt) {
            short8 bE = *reinterpret_cast<const short8*>(WeT + (nt * 16 + ln) * 160 + kk);
            accE[nt] = MFMA16(af, bE, accE[nt]);
        }
    }
    // epilogue (C layout: col=ln-group, row=lq*4+i) — wave-local rows
    #pragma unroll
    for (int nt = 0; nt < 4; ++nt) {
        const int col = nt * 16 + ln;
        const float bE = be[col], bS = bs[col];
        #pragma unroll
        for (int i = 0; i < 4; ++i) {
            const int row = wv * 16 + lq * 4 + i;
            Eb[row * ST + col] = f2bf(fmaxf(accE[nt][i] + bE, 0.f));
            Tb[row * ST + col] = f2bf(fmaxf(accS[nt][i] + bS, 0.f));
        }
    }
    wait_lgkm();   // wave-local: phase 2 reads the rows this wave just wrote

    // ======== Phase 2a: Sel = Senc@Wsel (Tb -> Tb, wave-local) ========
    floatx4 accSel[4] = {z, z, z, z};
    #pragma unroll
    for (int s = 0; s < 2; ++s) {
        short8 af = *reinterpret_cast<const short8*>(Tb + rA * ST + s * 32 + lq * 8);
        #pragma unroll
        for (int nt = 0; nt < 4; ++nt)
            accSel[nt] = MFMA16(af, *reinterpret_cast<const short8*>(WselT + (nt * 16 + ln) * 64 + s * 32 + lq * 8), accSel[nt]);
    }
    // overwrite Senc with Sel: write data depends on all lanes' reads via MFMA
    #pragma unroll
    for (int nt = 0; nt < 4; ++nt)
        #pragma unroll
        for (int i = 0; i < 4; ++i)
            Tb[(wv * 16 + lq * 4 + i) * ST + nt * 16 + ln] = f2bf(accSel[nt][i]);

    // ======== Phase 2b: K = E@Wk ; V = relu(E@Wv+bv) ========
    floatx4 accK[4] = {z, z, z, z}, accV[4] = {z, z, z, z};
    #pragma unroll
    for (int s = 0; s < 2; ++s) {
        short8 af = *reinterpret_cast<const short8*>(Eb + rA * ST + s * 32 + lq * 8);
        #pragma unroll
        for (int nt = 0; nt < 4; ++nt) {
            accK[nt] = MFMA16(af, *reinterpret_cast<const short8*>(WkT + (nt * 16 + ln) * 64 + s * 32 + lq * 8), accK[nt]);
            accV[nt] = MFMA16(af, *reinterpret_cast<const short8*>(WvT + (nt * 16 + ln) * 64 + s * 32 + lq * 8), accV[nt]);
        }
    }
    #pragma unroll
    for (int nt = 0; nt < 4; ++nt) {
        const int col = nt * 16 + ln;
        const float bV = bv[col];
        #pragma unroll
        for (int i = 0; i < 4; ++i) {
            const int row = wv * 16 + lq * 4 + i;
            Kb[row * ST + col] = f2bf(accK[nt][i]);
            Vb[row * ST + col] = f2bf(fmaxf(accV[nt][i] + bV, 0.f));
        }
    }
    lds_barrier();   // Kb/Vb read cross-wave below

    // ======== Phase 3: exclude-self attention, 1 thread per (row, head) ========
    {
        const int r3 = tid >> 2, hn = tid & 3;   // r3 is in this wave's 16-row range
        const int a3 = r3 >> 3, bl3 = r3 & 7;
        const int co = hn * 16;
        float selv[16];
        short8 s0 = *reinterpret_cast<const short8*>(Tb + r3 * ST + co);
        short8 s1 = *reinterpret_cast<const short8*>(Tb + r3 * ST + co + 8);
        #pragma unroll
        for (int d = 0; d < 8; ++d) { selv[d] = bf2f(s0[d]); selv[d + 8] = bf2f(s1[d]); }
        float lg[8];
        #pragma unroll
        for (int j = 0; j < 8; ++j) {
            const int rj = j * 8 + bl3;
            short8 k0 = *reinterpret_cast<const short8*>(Kb + rj * ST + co);
            short8 k1 = *reinterpret_cast<const short8*>(Kb + rj * ST + co + 8);
            float acc = 0.f;
            #pragma unroll
            for (int d = 0; d < 8; ++d) acc += selv[d] * bf2f(k0[d]) + selv[d + 8] * bf2f(k1[d]);
            lg[j] = (j == a3) ? -1e9f : acc * 0.25f;   // 1/sqrt(16)
        }
        float m = lg[0];
        #pragma unroll
        for (int j = 1; j < 8; ++j) m = fmaxf(m, lg[j]);
        float e[8], ssum = 0.f;
        #pragma unroll
        for (int j = 0; j < 8; ++j) { e[j] = __expf(lg[j] - m); ssum += e[j]; }
        const float inv = 1.f / ssum;
        float oth[16];
        #pragma unroll
        for (int d = 0; d < 16; ++d) oth[d] = 0.f;
        #pragma unroll
        for (int j = 0; j < 8; ++j) {
            const float wj = e[j] * inv;
            const int rj = j * 8 + bl3;
            short8 v0 = *reinterpret_cast<const short8*>(Vb + rj * ST + co);
            short8 v1 = *reinterpret_cast<const short8*>(Vb + rj * ST + co + 8);
            #pragma unroll
            for (int d = 0; d < 8; ++d) { oth[d] += wj * bf2f(v0[d]); oth[d + 8] += wj * bf2f(v1[d]); }
        }
        short8 o0, o1;
        #pragma unroll
        for (int d = 0; d < 8; ++d) { o0[d] = f2bf(oth[d]); o1[d] = f2bf(oth[d + 8]); }
        // overwrite own Sel slot with 'other' — unique (row,head) owner, no race
        *reinterpret_cast<short8*>(Tb + r3 * ST + co)     = o0;
        *reinterpret_cast<short8*>(Tb + r3 * ST + co + 8) = o1;
    }
    wait_lgkm();   // wave-local: phase 4 reads rows this wave's threads wrote

    // ======== Phase 4: h = relu([E|other]@W1+b1) ; q = h@W2 + b2 ========
    floatx4 accH[4] = {z, z, z, z};
    #pragma unroll
    for (int s = 0; s < 4; ++s) {
        short8 af = (s < 2)
            ? *reinterpret_cast<const short8*>(Eb + rA * ST + s * 32 + lq * 8)
            : *reinterpret_cast<const short8*>(Tb + rA * ST + (s - 2) * 32 + lq * 8);
        #pragma unroll
        for (int nt = 0; nt < 4; ++nt)
            accH[nt] = MFMA16(af, *reinterpret_cast<const short8*>(W1T + (nt * 16 + ln) * 128 + s * 32 + lq * 8), accH[nt]);
    }
    float p0 = 0.f, p1 = 0.f, p2 = 0.f, p3 = 0.f;
    #pragma unroll
    for (int nt = 0; nt < 4; ++nt) {
        const int col = nt * 16 + ln;
        const float w2v = W2[col], bb = b1[col];
        p0 += fmaxf(accH[nt][0] + bb, 0.f) * w2v;
        p1 += fmaxf(accH[nt][1] + bb, 0.f) * w2v;
        p2 += fmaxf(accH[nt][2] + bb, 0.f) * w2v;
        p3 += fmaxf(accH[nt][3] + bb, 0.f) * w2v;
    }
    #pragma unroll
    for (int mk = 1; mk < 16; mk <<= 1) {
        p0 += __shfl_xor(p0, mk, 64);
        p1 += __shfl_xor(p1, mk, 64);
        p2 += __shfl_xor(p2, mk, 64);
        p3 += __shfl_xor(p3, mk, 64);
    }
    if (ln == 0) {
        const float b2v = b2[0];
        float pr[4] = {p0, p1, p2, p3};
        #pragma unroll
        for (int i = 0; i < 4; ++i) {
            const int r = wv * 16 + lq * 4 + i;
            out[(long)(r >> 3) * B_N + b0 + (r & 7)] = pr[i] + b2v;
        }
    }
}

extern "C" void kernel_launch(void* const* d_in, const int* in_sizes, int n_in,
                              void* d_out, int out_size, void* d_ws, size_t ws_size,
                              hipStream_t stream) {
    const float* states  = (const float*)d_in[0];
    const float* actions = (const float*)d_in[1];
    const float* Ws      = (const float*)d_in[2];
    const float* bs      = (const float*)d_in[3];
    const float* We      = (const float*)d_in[4];
    const float* be      = (const float*)d_in[5];
    const float* Wk      = (const float*)d_in[6];
    const float* Wsel    = (const float*)d_in[7];
    const float* Wv      = (const float*)d_in[8];
    const float* bv      = (const float*)d_in[9];
    const float* W1      = (const float*)d_in[10];
    const float* b1      = (const float*)d_in[11];
    const float* W2      = (const float*)d_in[12];
    const float* b2      = (const float*)d_in[13];
    short* wts = (short*)d_ws;
    float* out = (float*)d_out;

    prep_weights<<<(W_TOTAL + 255) / 256, 256, 0, stream>>>(Ws, We, Wk, Wsel, Wv, W1, wts);
    attention_critic_mfma<<<B_N / 8, 256, 0, stream>>>(
        states, actions, bs, be, bv, b1, W2, b2, wts, out);
}

// Round 5
// 260.490 us; speedup vs baseline: 2.3510x; 1.2919x over previous
//
#include <hip/hip_runtime.h>
#include <hip/hip_bf16.h>

// A=8, B=32768, S=128, AD=16, H=64, NH=4, D=16
#define A_N 8
#define B_N 32768
#define S_N 128
#define AD_N 16

typedef __attribute__((ext_vector_type(8))) short short8;
typedef __attribute__((ext_vector_type(4))) float floatx4;

#define MFMA16(a, b, c) __builtin_amdgcn_mfma_f32_16x16x32_bf16(a, b, c, 0, 0, 0)

__device__ __forceinline__ short f2bf(float f) {
    __hip_bfloat16 h = __float2bfloat16(f);
    return *reinterpret_cast<short*>(&h);
}
__device__ __forceinline__ float bf2f(short s) {
    return __uint_as_float(((unsigned)(unsigned short)s) << 16);
}
__device__ __forceinline__ void pk2(short8& r, int i, float a, float b) {
    __hip_bfloat162 p = __float22bfloat162_rn(make_float2(a, b));
    short2 s = *reinterpret_cast<short2*>(&p);
    r[i] = s.x; r[i + 1] = s.y;
}
__device__ __forceinline__ short8 cvt8(float4 x0, float4 x1) {
    short8 r;
    pk2(r, 0, x0.x, x0.y); pk2(r, 2, x0.z, x0.w);
    pk2(r, 4, x1.x, x1.y); pk2(r, 6, x1.z, x1.w);
    return r;
}
// wave-local LDS ordering fence
__device__ __forceinline__ void wait_lgkm() {
    asm volatile("s_waitcnt lgkmcnt(0)" ::: "memory");
}
// cross-wave barrier WITHOUT vmcnt drain (register prefetch stays in flight)
__device__ __forceinline__ void lds_barrier() {
    asm volatile("s_waitcnt lgkmcnt(0)\ns_barrier" ::: "memory");
}

// ---- weight prep into d_ws: bf16 [n][k], rows padded for LDS bank spread ----
// shorts: WeT[64][160]@0 | WsT[64][136]@10240 | WkT[64][72]@18944
//         WselT[64][72]@23552 | WvT[64][72]@28160 | W1T[64][136]@32768
#define W_TOTAL 41472   // shorts = 82944 B = 81 KiB chunks of 1 KiB exactly
#define OFF_Ws 10240
#define OFF_Wk 18944
#define OFF_Wsel 23552
#define OFF_Wv 28160
#define OFF_W1 32768

__global__ void prep_weights(const float* __restrict__ Ws, const float* __restrict__ We,
                             const float* __restrict__ Wk, const float* __restrict__ Wsel,
                             const float* __restrict__ Wv, const float* __restrict__ W1,
                             short* __restrict__ w) {
    int idx = blockIdx.x * 256 + threadIdx.x;
    if (idx >= W_TOTAL) return;
    float v;
    if (idx < OFF_Ws)        { int n = idx / 160, k = idx % 160; v = (k < 144) ? We[k * 64 + n] : 0.f; }
    else if (idx < OFF_Wk)   { int i = idx - OFF_Ws;  int n = i / 136, k = i % 136; v = (k < 128) ? Ws[k * 64 + n] : 0.f; }
    else if (idx < OFF_Wsel) { int i = idx - OFF_Wk;  int n = i / 72,  k = i % 72;  v = (k < 64) ? Wk[(n >> 4) * 1024 + k * 16 + (n & 15)] : 0.f; }
    else if (idx < OFF_Wv)   { int i = idx - OFF_Wsel;int n = i / 72,  k = i % 72;  v = (k < 64) ? Wsel[(n >> 4) * 1024 + k * 16 + (n & 15)] : 0.f; }
    else if (idx < OFF_W1)   { int i = idx - OFF_Wv;  int n = i / 72,  k = i % 72;  v = (k < 64) ? Wv[(n >> 4) * 1024 + k * 16 + (n & 15)] : 0.f; }
    else                     { int i = idx - OFF_W1;  int n = i / 136, k = i % 136; v = (k < 128) ? W1[k * 64 + n] : 0.f; }
    w[idx] = f2bf(v);
}

// ---- LDS partition (shorts) ----
#define ST 72            // activation row stride: 144 B, 16B-mult, odd dword-quad stride
#define OFF_Eb 41472
#define OFF_Tb 50688
#define OFF_Kb 59904
#define OFF_Vb 69120
#define SMEM_TOT 78336   // 156672 B <= 160 KiB gfx950 workgroup LDS

#define TILES 4          // 16 batches per tile, 64 batches per block, grid=512

__global__ __launch_bounds__(512, 2)
void attention_critic_mfma(
    const float* __restrict__ states, const float* __restrict__ actions,
    const float* __restrict__ bs, const float* __restrict__ be,
    const float* __restrict__ bv, const float* __restrict__ b1,
    const float* __restrict__ W2, const float* __restrict__ b2,
    const short* __restrict__ wts, float* __restrict__ out)
{
    __shared__ __align__(16) short smem[SMEM_TOT];
    short* lWe   = smem;             // [64][160]
    short* lWs   = smem + OFF_Ws;    // [64][136]
    short* lWk   = smem + OFF_Wk;    // [64][72]
    short* lWsel = smem + OFF_Wsel;  // [64][72]
    short* lWv   = smem + OFF_Wv;    // [64][72]
    short* lW1   = smem + OFF_W1;    // [64][136]
    short* Eb    = smem + OFF_Eb;    // [128][ST] sa_enc
    short* Tb    = smem + OFF_Tb;    // [128][ST] s_enc -> Sel -> other (wave-local reuse)
    short* Kb    = smem + OFF_Kb;    // [128][ST] cross-wave in phase 3
    short* Vb    = smem + OFF_Vb;    // [128][ST] cross-wave in phase 3

    const int tid  = threadIdx.x;
    const int wv   = tid >> 6;       // wave 0..7 = agent = M-tile
    const int lane = tid & 63;
    const int lq   = lane >> 4;
    const int ln   = lane & 15;
    const int rA   = wv * 16 + ln;   // A-fragment row (0..127)
    const int bbase = blockIdx.x * (TILES * 16);

    // ---- stage all weights into LDS (81 x 1KiB chunks, global_load_lds w=16) ----
    for (int c = wv; c < 81; c += 8) {
        const unsigned int* g = reinterpret_cast<const unsigned int*>(wts + c * 512) + lane * 4;
        __builtin_amdgcn_global_load_lds(g, reinterpret_cast<unsigned int*>(smem + c * 512), 16, 0, 0);
    }

    // ---- input pointers: agent = wv, batch = bbase + t*16 + ln ----
    const float* srow = states  + ((long)wv * B_N + bbase + ln) * S_N;
    const float* arow = actions + ((long)wv * B_N + bbase + ln) * AD_N;

    // prologue: prefetch tile 0 inputs into registers
    float4 ps[8]; float4 pa[2];
    #pragma unroll
    for (int s = 0; s < 4; ++s) {
        ps[2 * s]     = *reinterpret_cast<const float4*>(srow + s * 32 + lq * 8);
        ps[2 * s + 1] = *reinterpret_cast<const float4*>(srow + s * 32 + lq * 8 + 4);
    }
    if (lq < 2) {
        pa[0] = *reinterpret_cast<const float4*>(arow + lq * 8);
        pa[1] = *reinterpret_cast<const float4*>(arow + lq * 8 + 4);
    }
    __syncthreads();   // weights staged (drains vmcnt incl. global_load_lds)

    const floatx4 z = {0.f, 0.f, 0.f, 0.f};

    #pragma unroll 1
    for (int t = 0; t < TILES; ++t) {
        const int b0 = bbase + t * 16;

        // ======== Phase 1: E = relu(X@We+be), Senc = relu(states@Ws+bs) ========
        floatx4 accE[4] = {z, z, z, z};
        floatx4 accS[4] = {z, z, z, z};
        #pragma unroll
        for (int s = 0; s < 4; ++s) {
            const int kk = s * 32 + lq * 8;
            short8 af = cvt8(ps[2 * s], ps[2 * s + 1]);
            #pragma unroll
            for (int nt = 0; nt < 4; ++nt) {
                short8 bE = *reinterpret_cast<const short8*>(lWe + (nt * 16 + ln) * 160 + kk);
                short8 bS = *reinterpret_cast<const short8*>(lWs + (nt * 16 + ln) * 136 + kk);
                accE[nt] = MFMA16(af, bE, accE[nt]);
                accS[nt] = MFMA16(af, bS, accS[nt]);
            }
        }
        {   // k tail 128..159: actions for k<144, zero pad beyond
            const int kk = 128 + lq * 8;
            short8 af = {0, 0, 0, 0, 0, 0, 0, 0};
            if (lq < 2) af = cvt8(pa[0], pa[1]);
            #pragma unroll
            for (int nt = 0; nt < 4; ++nt) {
                short8 bE = *reinterpret_cast<const short8*>(lWe + (nt * 16 + ln) * 160 + kk);
                accE[nt] = MFMA16(af, bE, accE[nt]);
            }
        }

        // prefetch next tile's inputs (dead registers; vmcnt survives lds_barrier)
        if (t + 1 < TILES) {
            srow += 16 * S_N; arow += 16 * AD_N;
            #pragma unroll
            for (int s = 0; s < 4; ++s) {
                ps[2 * s]     = *reinterpret_cast<const float4*>(srow + s * 32 + lq * 8);
                ps[2 * s + 1] = *reinterpret_cast<const float4*>(srow + s * 32 + lq * 8 + 4);
            }
            if (lq < 2) {
                pa[0] = *reinterpret_cast<const float4*>(arow + lq * 8);
                pa[1] = *reinterpret_cast<const float4*>(arow + lq * 8 + 4);
            }
        }

        // phase-1 epilogue (C layout: col=ln-group, row=lq*4+i) — wave-local rows
        #pragma unroll
        for (int nt = 0; nt < 4; ++nt) {
            const int col = nt * 16 + ln;
            const float bE = be[col], bS = bs[col];
            #pragma unroll
            for (int i = 0; i < 4; ++i) {
                const int row = wv * 16 + lq * 4 + i;
                Eb[row * ST + col] = f2bf(fmaxf(accE[nt][i] + bE, 0.f));
                Tb[row * ST + col] = f2bf(fmaxf(accS[nt][i] + bS, 0.f));
            }
        }
        wait_lgkm();   // wave-local: phase 2 reads rows this wave just wrote

        // ======== Phase 2a: Sel = Senc@Wsel (Tb -> Tb, wave-local) ========
        floatx4 accSel[4] = {z, z, z, z};
        #pragma unroll
        for (int s = 0; s < 2; ++s) {
            short8 af = *reinterpret_cast<const short8*>(Tb + rA * ST + s * 32 + lq * 8);
            #pragma unroll
            for (int nt = 0; nt < 4; ++nt)
                accSel[nt] = MFMA16(af, *reinterpret_cast<const short8*>(lWsel + (nt * 16 + ln) * 72 + s * 32 + lq * 8), accSel[nt]);
        }
        #pragma unroll
        for (int nt = 0; nt < 4; ++nt)
            #pragma unroll
            for (int i = 0; i < 4; ++i)
                Tb[(wv * 16 + lq * 4 + i) * ST + nt * 16 + ln] = f2bf(accSel[nt][i]);

        // ======== Phase 2b: K = E@Wk ; V = relu(E@Wv+bv) ========
        floatx4 accK[4] = {z, z, z, z}, accV[4] = {z, z, z, z};
        #pragma unroll
        for (int s = 0; s < 2; ++s) {
            short8 af = *reinterpret_cast<const short8*>(Eb + rA * ST + s * 32 + lq * 8);
            #pragma unroll
            for (int nt = 0; nt < 4; ++nt) {
                accK[nt] = MFMA16(af, *reinterpret_cast<const short8*>(lWk + (nt * 16 + ln) * 72 + s * 32 + lq * 8), accK[nt]);
                accV[nt] = MFMA16(af, *reinterpret_cast<const short8*>(lWv + (nt * 16 + ln) * 72 + s * 32 + lq * 8), accV[nt]);
            }
        }
        #pragma unroll
        for (int nt = 0; nt < 4; ++nt) {
            const int col = nt * 16 + ln;
            const float bV = bv[col];
            #pragma unroll
            for (int i = 0; i < 4; ++i) {
                const int row = wv * 16 + lq * 4 + i;
                Kb[row * ST + col] = f2bf(accK[nt][i]);
                Vb[row * ST + col] = f2bf(fmaxf(accV[nt][i] + bV, 0.f));
            }
        }
        lds_barrier();   // Kb/Vb read cross-wave below

        // ======== Phase 3: exclude-self attention, 1 thread per (row, head) ========
        {
            const int r3 = tid >> 2, hn = tid & 3;   // r3 in this wave's 16-row range
            const int a3 = r3 >> 4, bl3 = r3 & 15;
            const int co = hn * 16;
            float selv[16];
            short8 s0 = *reinterpret_cast<const short8*>(Tb + r3 * ST + co);
            short8 s1 = *reinterpret_cast<const short8*>(Tb + r3 * ST + co + 8);
            #pragma unroll
            for (int d = 0; d < 8; ++d) { selv[d] = bf2f(s0[d]); selv[d + 8] = bf2f(s1[d]); }
            float lg[8];
            #pragma unroll
            for (int j = 0; j < 8; ++j) {
                const int rj = j * 16 + bl3;
                short8 k0 = *reinterpret_cast<const short8*>(Kb + rj * ST + co);
                short8 k1 = *reinterpret_cast<const short8*>(Kb + rj * ST + co + 8);
                float acc = 0.f;
                #pragma unroll
                for (int d = 0; d < 8; ++d) acc += selv[d] * bf2f(k0[d]) + selv[d + 8] * bf2f(k1[d]);
                lg[j] = (j == a3) ? -1e9f : acc * 0.25f;   // 1/sqrt(16)
            }
            float m = lg[0];
            #pragma unroll
            for (int j = 1; j < 8; ++j) m = fmaxf(m, lg[j]);
            float e[8], ssum = 0.f;
            #pragma unroll
            for (int j = 0; j < 8; ++j) { e[j] = __expf(lg[j] - m); ssum += e[j]; }
            const float inv = 1.f / ssum;
            float oth[16];
            #pragma unroll
            for (int d = 0; d < 16; ++d) oth[d] = 0.f;
            #pragma unroll
            for (int j = 0; j < 8; ++j) {
                const float wj = e[j] * inv;
                const int rj = j * 16 + bl3;
                short8 v0 = *reinterpret_cast<const short8*>(Vb + rj * ST + co);
                short8 v1 = *reinterpret_cast<const short8*>(Vb + rj * ST + co + 8);
                #pragma unroll
                for (int d = 0; d < 8; ++d) { oth[d] += wj * bf2f(v0[d]); oth[d + 8] += wj * bf2f(v1[d]); }
            }
            short8 o0, o1;
            #pragma unroll
            for (int d = 0; d < 8; ++d) { o0[d] = f2bf(oth[d]); o1[d] = f2bf(oth[d + 8]); }
            // own (row,head) slot — unique owner, wave-local rows
            *reinterpret_cast<short8*>(Tb + r3 * ST + co)     = o0;
            *reinterpret_cast<short8*>(Tb + r3 * ST + co + 8) = o1;
        }
        wait_lgkm();   // wave-local: phase 4 reads rows this wave's threads wrote

        // ======== Phase 4: h = relu([E|other]@W1+b1) ; q = h@W2 + b2 ========
        floatx4 accH[4] = {z, z, z, z};
        #pragma unroll
        for (int s = 0; s < 4; ++s) {
            short8 af = (s < 2)
                ? *reinterpret_cast<const short8*>(Eb + rA * ST + s * 32 + lq * 8)
                : *reinterpret_cast<const short8*>(Tb + rA * ST + (s - 2) * 32 + lq * 8);
            #pragma unroll
            for (int nt = 0; nt < 4; ++nt)
                accH[nt] = MFMA16(af, *reinterpret_cast<const short8*>(lW1 + (nt * 16 + ln) * 136 + s * 32 + lq * 8), accH[nt]);
        }
        float p0 = 0.f, p1 = 0.f, p2 = 0.f, p3 = 0.f;
        #pragma unroll
        for (int nt = 0; nt < 4; ++nt) {
            const int col = nt * 16 + ln;
            const float w2v = W2[col], bb = b1[col];
            p0 += fmaxf(accH[nt][0] + bb, 0.f) * w2v;
            p1 += fmaxf(accH[nt][1] + bb, 0.f) * w2v;
            p2 += fmaxf(accH[nt][2] + bb, 0.f) * w2v;
            p3 += fmaxf(accH[nt][3] + bb, 0.f) * w2v;
        }
        #pragma unroll
        for (int mk = 1; mk < 16; mk <<= 1) {
            p0 += __shfl_xor(p0, mk, 64);
            p1 += __shfl_xor(p1, mk, 64);
            p2 += __shfl_xor(p2, mk, 64);
            p3 += __shfl_xor(p3, mk, 64);
        }
        if (ln == 0) {
            const float b2v = b2[0];
            float pr[4] = {p0, p1, p2, p3};
            #pragma unroll
            for (int i = 0; i < 4; ++i)
                out[(long)wv * B_N + b0 + lq * 4 + i] = pr[i] + b2v;
        }
        lds_barrier();   // Kb/Vb reused by next tile's phase 2b
    }
}

extern "C" void kernel_launch(void* const* d_in, const int* in_sizes, int n_in,
                              void* d_out, int out_size, void* d_ws, size_t ws_size,
                              hipStream_t stream) {
    const float* states  = (const float*)d_in[0];
    const float* actions = (const float*)d_in[1];
    const float* Ws      = (const float*)d_in[2];
    const float* bs      = (const float*)d_in[3];
    const float* We      = (const float*)d_in[4];
    const float* be      = (const float*)d_in[5];
    const float* Wk      = (const float*)d_in[6];
    const float* Wsel    = (const float*)d_in[7];
    const float* Wv      = (const float*)d_in[8];
    const float* bv      = (const float*)d_in[9];
    const float* W1      = (const float*)d_in[10];
    const float* b1      = (const float*)d_in[11];
    const float* W2      = (const float*)d_in[12];
    const float* b2      = (const float*)d_in[13];
    short* wts = (short*)d_ws;
    float* out = (float*)d_out;

    prep_weights<<<(W_TOTAL + 255) / 256, 256, 0, stream>>>(Ws, We, Wk, Wsel, Wv, W1, wts);
    attention_critic_mfma<<<B_N / (TILES * 16), 512, 0, stream>>>(
        states, actions, bs, be, bv, b1, W2, b2, wts, out);
}

// Round 6
// 257.094 us; speedup vs baseline: 2.3821x; 1.0132x over previous
//
#include <hip/hip_runtime.h>
#include <hip/hip_bf16.h>

// A=8, B=32768, S=128, AD=16, H=64, NH=4, D=16
#define A_N 8
#define B_N 32768
#define S_N 128
#define AD_N 16

typedef __attribute__((ext_vector_type(8))) short short8;
typedef __attribute__((ext_vector_type(4))) float floatx4;

#define MFMA16(a, b, c) __builtin_amdgcn_mfma_f32_16x16x32_bf16(a, b, c, 0, 0, 0)

__device__ __forceinline__ short f2bf(float f) {
    __hip_bfloat16 h = __float2bfloat16(f);
    return *reinterpret_cast<short*>(&h);
}
__device__ __forceinline__ float bf2f(short s) {
    return __uint_as_float(((unsigned)(unsigned short)s) << 16);
}
__device__ __forceinline__ void pk2(short8& r, int i, float a, float b) {
    __hip_bfloat162 p = __float22bfloat162_rn(make_float2(a, b));
    short2 s = *reinterpret_cast<short2*>(&p);
    r[i] = s.x; r[i + 1] = s.y;
}
__device__ __forceinline__ short8 cvt8(float4 x0, float4 x1) {
    short8 r;
    pk2(r, 0, x0.x, x0.y); pk2(r, 2, x0.z, x0.w);
    pk2(r, 4, x1.x, x1.y); pk2(r, 6, x1.z, x1.w);
    return r;
}
// wave-local LDS ordering fence: DS pipe is in-order per wave; lgkmcnt(0)
// guarantees this wave's writes are visible to this wave's subsequent reads.
__device__ __forceinline__ void wait_lgkm() {
    asm volatile("s_waitcnt lgkmcnt(0)" ::: "memory");
}

// ---- weight prep into d_ws: bf16 [n][k], rows padded for LDS bank spread ----
// shorts: WeT[64][168]@0 | WsT[64][136]@10752 | WkT[64][72]@19456
//         WselT[64][72]@24064 | WvT[64][72]@28672 | W1T[64][136]@33280
// stride choices: 168 shorts = 84 dw (gcd(84%32=20,32)=4 -> uniform banks);
// 136 = 68 dw (=4 mod 32, uniform); 72 = 36 dw (=4 mod 32, uniform).
#define OFF_Ws 10752
#define OFF_Wk 19456
#define OFF_Wsel 24064
#define OFF_Wv 28672
#define OFF_W1 33280
#define W_TOTAL 41984    // shorts = 83968 B = 82 x 1 KiB chunks

__global__ void prep_weights(const float* __restrict__ Ws, const float* __restrict__ We,
                             const float* __restrict__ Wk, const float* __restrict__ Wsel,
                             const float* __restrict__ Wv, const float* __restrict__ W1,
                             short* __restrict__ w) {
    int idx = blockIdx.x * 256 + threadIdx.x;
    if (idx >= W_TOTAL) return;
    float v;
    if (idx < OFF_Ws)        { int n = idx / 168, k = idx % 168; v = (k < 144) ? We[k * 64 + n] : 0.f; }
    else if (idx < OFF_Wk)   { int i = idx - OFF_Ws;  int n = i / 136, k = i % 136; v = (k < 128) ? Ws[k * 64 + n] : 0.f; }
    else if (idx < OFF_Wsel) { int i = idx - OFF_Wk;  int n = i / 72,  k = i % 72;  v = (k < 64) ? Wk[(n >> 4) * 1024 + k * 16 + (n & 15)] : 0.f; }
    else if (idx < OFF_Wv)   { int i = idx - OFF_Wsel;int n = i / 72,  k = i % 72;  v = (k < 64) ? Wsel[(n >> 4) * 1024 + k * 16 + (n & 15)] : 0.f; }
    else if (idx < OFF_W1)   { int i = idx - OFF_Wv;  int n = i / 72,  k = i % 72;  v = (k < 64) ? Wv[(n >> 4) * 1024 + k * 16 + (n & 15)] : 0.f; }
    else                     { int i = idx - OFF_W1;  int n = i / 136, k = i % 136; v = (k < 128) ? W1[k * 64 + n] : 0.f; }
    w[idx] = f2bf(v);
}

// ---- LDS partition (shorts) ----
#define ST 72            // activation row stride: 144 B (36 dw = 4 mod 32, uniform)
#define OFF_Eb 41984
#define OFF_Tb 51200
#define OFF_Kb 60416
#define OFF_Vb 69632
#define SMEM_TOT 78848   // 157696 B <= 160 KiB gfx950 workgroup LDS

#define TILES 4          // 16 batches per tile, 64 batches per block, grid=512

// Row ownership: wave wv owns 16 rows = 2 batches x 8 agents.
// Row m (0..15) <-> (a = m&7, bl = m>>3); batch = b0 + wv*2 + bl.
// Attention mixes agents within a batch -> entirely WAVE-LOCAL -> no barriers
// in the tile loop; waves free-run and self-pipeline across tiles.
__global__ __launch_bounds__(512, 2)
void attention_critic_mfma(
    const float* __restrict__ states, const float* __restrict__ actions,
    const float* __restrict__ bs, const float* __restrict__ be,
    const float* __restrict__ bv, const float* __restrict__ b1,
    const float* __restrict__ W2, const float* __restrict__ b2,
    const short* __restrict__ wts, float* __restrict__ out)
{
    __shared__ __align__(16) short smem[SMEM_TOT];
    short* lWe   = smem;             // [64][168]
    short* lWs   = smem + OFF_Ws;    // [64][136]
    short* lWk   = smem + OFF_Wk;    // [64][72]
    short* lWsel = smem + OFF_Wsel;  // [64][72]
    short* lWv   = smem + OFF_Wv;    // [64][72]
    short* lW1   = smem + OFF_W1;    // [64][136]
    short* Eb    = smem + OFF_Eb;    // [128][ST] sa_enc           (wave-local)
    short* Tb    = smem + OFF_Tb;    // [128][ST] s_enc->Sel->other (wave-local)
    short* Kb    = smem + OFF_Kb;    // [128][ST] keys              (wave-local now)
    short* Vb    = smem + OFF_Vb;    // [128][ST] values            (wave-local now)

    const int tid  = threadIdx.x;
    const int wv   = tid >> 6;       // wave 0..7 = 2-batch group
    const int lane = tid & 63;
    const int lq   = lane >> 4;
    const int ln   = lane & 15;
    const int rA   = wv * 16 + ln;   // A-fragment LDS row for this lane
    const int bbase = blockIdx.x * (TILES * 16);

    // ---- stage all weights into LDS (82 x 1KiB chunks, global_load_lds w=16) ----
    for (int c = wv; c < 82; c += 8) {
        const unsigned int* g = reinterpret_cast<const unsigned int*>(wts + c * 512) + lane * 4;
        __builtin_amdgcn_global_load_lds(g, reinterpret_cast<unsigned int*>(smem + c * 512), 16, 0, 0);
    }

    // ---- input pointers: lane ln -> row m=ln: a = ln&7, bl = ln>>3 ----
    const int aA  = ln & 7;
    const int blA = ln >> 3;
    const float* srow = states  + ((long)aA * B_N + bbase + wv * 2 + blA) * S_N;
    const float* arow = actions + ((long)aA * B_N + bbase + wv * 2 + blA) * AD_N;

    // prologue: prefetch tile 0 inputs into registers
    float4 ps[8]; float4 pa[2];
    #pragma unroll
    for (int s = 0; s < 4; ++s) {
        ps[2 * s]     = *reinterpret_cast<const float4*>(srow + s * 32 + lq * 8);
        ps[2 * s + 1] = *reinterpret_cast<const float4*>(srow + s * 32 + lq * 8 + 4);
    }
    if (lq < 2) {
        pa[0] = *reinterpret_cast<const float4*>(arow + lq * 8);
        pa[1] = *reinterpret_cast<const float4*>(arow + lq * 8 + 4);
    }
    __syncthreads();   // weights staged (drains vmcnt incl. global_load_lds)

    const floatx4 z = {0.f, 0.f, 0.f, 0.f};

    #pragma unroll 1
    for (int t = 0; t < TILES; ++t) {
        const int b0 = bbase + t * 16;

        // ======== Phase 1: E = relu(X@We+be), Senc = relu(states@Ws+bs) ========
        floatx4 accE[4] = {z, z, z, z};
        floatx4 accS[4] = {z, z, z, z};
        #pragma unroll
        for (int s = 0; s < 4; ++s) {
            const int kk = s * 32 + lq * 8;
            short8 af = cvt8(ps[2 * s], ps[2 * s + 1]);
            #pragma unroll
            for (int nt = 0; nt < 4; ++nt) {
                short8 bE = *reinterpret_cast<const short8*>(lWe + (nt * 16 + ln) * 168 + kk);
                short8 bS = *reinterpret_cast<const short8*>(lWs + (nt * 16 + ln) * 136 + kk);
                accE[nt] = MFMA16(af, bE, accE[nt]);
                accS[nt] = MFMA16(af, bS, accS[nt]);
            }
        }
        {   // k tail 128..159: actions for k<144, zero pad beyond
            const int kk = 128 + lq * 8;
            short8 af = {0, 0, 0, 0, 0, 0, 0, 0};
            if (lq < 2) af = cvt8(pa[0], pa[1]);
            #pragma unroll
            for (int nt = 0; nt < 4; ++nt) {
                short8 bE = *reinterpret_cast<const short8*>(lWe + (nt * 16 + ln) * 168 + kk);
                accE[nt] = MFMA16(af, bE, accE[nt]);
            }
        }

        // prefetch next tile's inputs (dead registers; no barriers ahead)
        if (t + 1 < TILES) {
            srow += 16 * S_N; arow += 16 * AD_N;
            #pragma unroll
            for (int s = 0; s < 4; ++s) {
                ps[2 * s]     = *reinterpret_cast<const float4*>(srow + s * 32 + lq * 8);
                ps[2 * s + 1] = *reinterpret_cast<const float4*>(srow + s * 32 + lq * 8 + 4);
            }
            if (lq < 2) {
                pa[0] = *reinterpret_cast<const float4*>(arow + lq * 8);
                pa[1] = *reinterpret_cast<const float4*>(arow + lq * 8 + 4);
            }
        }

        // phase-1 epilogue (C layout: col=nt*16+ln, row=lq*4+i) — wave-local rows
        #pragma unroll
        for (int nt = 0; nt < 4; ++nt) {
            const int col = nt * 16 + ln;
            const float bE = be[col], bS = bs[col];
            #pragma unroll
            for (int i = 0; i < 4; ++i) {
                const int row = wv * 16 + lq * 4 + i;
                Eb[row * ST + col] = f2bf(fmaxf(accE[nt][i] + bE, 0.f));
                Tb[row * ST + col] = f2bf(fmaxf(accS[nt][i] + bS, 0.f));
            }
        }
        wait_lgkm();

        // ======== Phase 2a: Sel = Senc@Wsel (Tb -> Tb, wave-local) ========
        floatx4 accSel[4] = {z, z, z, z};
        #pragma unroll
        for (int s = 0; s < 2; ++s) {
            short8 af = *reinterpret_cast<const short8*>(Tb + rA * ST + s * 32 + lq * 8);
            #pragma unroll
            for (int nt = 0; nt < 4; ++nt)
                accSel[nt] = MFMA16(af, *reinterpret_cast<const short8*>(lWsel + (nt * 16 + ln) * 72 + s * 32 + lq * 8), accSel[nt]);
        }
        #pragma unroll
        for (int nt = 0; nt < 4; ++nt)
            #pragma unroll
            for (int i = 0; i < 4; ++i)
                Tb[(wv * 16 + lq * 4 + i) * ST + nt * 16 + ln] = f2bf(accSel[nt][i]);

        // ======== Phase 2b: K = E@Wk ; V = relu(E@Wv+bv) ========
        floatx4 accK[4] = {z, z, z, z}, accV[4] = {z, z, z, z};
        #pragma unroll
        for (int s = 0; s < 2; ++s) {
            short8 af = *reinterpret_cast<const short8*>(Eb + rA * ST + s * 32 + lq * 8);
            #pragma unroll
            for (int nt = 0; nt < 4; ++nt) {
                accK[nt] = MFMA16(af, *reinterpret_cast<const short8*>(lWk + (nt * 16 + ln) * 72 + s * 32 + lq * 8), accK[nt]);
                accV[nt] = MFMA16(af, *reinterpret_cast<const short8*>(lWv + (nt * 16 + ln) * 72 + s * 32 + lq * 8), accV[nt]);
            }
        }
        #pragma unroll
        for (int nt = 0; nt < 4; ++nt) {
            const int col = nt * 16 + ln;
            const float bV = bv[col];
            #pragma unroll
            for (int i = 0; i < 4; ++i) {
                const int row = wv * 16 + lq * 4 + i;
                Kb[row * ST + col] = f2bf(accK[nt][i]);
                Vb[row * ST + col] = f2bf(fmaxf(accV[nt][i] + bV, 0.f));
            }
        }
        wait_lgkm();   // wave-local: phase 3 reads rows this wave just wrote

        // ======== Phase 3: exclude-self attention, 1 lane per (row, head) ========
        {
            const int r3 = lane >> 2;          // wave-local row 0..15
            const int hn = lane & 3;
            const int a3 = r3 & 7;             // agent of this row
            const int rowbase = wv * 16 + (r3 & 8);   // rows of same batch, agents 0..7
            const int co = hn * 16;
            float selv[16];
            short8 s0 = *reinterpret_cast<const short8*>(Tb + (wv * 16 + r3) * ST + co);
            short8 s1 = *reinterpret_cast<const short8*>(Tb + (wv * 16 + r3) * ST + co + 8);
            #pragma unroll
            for (int d = 0; d < 8; ++d) { selv[d] = bf2f(s0[d]); selv[d + 8] = bf2f(s1[d]); }
            float lg[8];
            #pragma unroll
            for (int j = 0; j < 8; ++j) {
                const int rj = rowbase + j;
                short8 k0 = *reinterpret_cast<const short8*>(Kb + rj * ST + co);
                short8 k1 = *reinterpret_cast<const short8*>(Kb + rj * ST + co + 8);
                float acc = 0.f;
                #pragma unroll
                for (int d = 0; d < 8; ++d) acc += selv[d] * bf2f(k0[d]) + selv[d + 8] * bf2f(k1[d]);
                lg[j] = (j == a3) ? -1e9f : acc * 0.25f;   // 1/sqrt(16)
            }
            float m = lg[0];
            #pragma unroll
            for (int j = 1; j < 8; ++j) m = fmaxf(m, lg[j]);
            float e[8], ssum = 0.f;
            #pragma unroll
            for (int j = 0; j < 8; ++j) { e[j] = __expf(lg[j] - m); ssum += e[j]; }
            const float inv = 1.f / ssum;
            float oth[16];
            #pragma unroll
            for (int d = 0; d < 16; ++d) oth[d] = 0.f;
            #pragma unroll
            for (int j = 0; j < 8; ++j) {
                const float wj = e[j] * inv;
                const int rj = rowbase + j;
                short8 v0 = *reinterpret_cast<const short8*>(Vb + rj * ST + co);
                short8 v1 = *reinterpret_cast<const short8*>(Vb + rj * ST + co + 8);
                #pragma unroll
                for (int d = 0; d < 8; ++d) { oth[d] += wj * bf2f(v0[d]); oth[d + 8] += wj * bf2f(v1[d]); }
            }
            short8 o0, o1;
            #pragma unroll
            for (int d = 0; d < 8; ++d) { o0[d] = f2bf(oth[d]); o1[d] = f2bf(oth[d + 8]); }
            // own (row,head) slot — unique owner within wave
            *reinterpret_cast<short8*>(Tb + (wv * 16 + r3) * ST + co)     = o0;
            *reinterpret_cast<short8*>(Tb + (wv * 16 + r3) * ST + co + 8) = o1;
        }
        wait_lgkm();   // wave-local: phase 4 reads rows this wave's lanes wrote

        // ======== Phase 4: h = relu([E|other]@W1+b1) ; q = h@W2 + b2 ========
        floatx4 accH[4] = {z, z, z, z};
        #pragma unroll
        for (int s = 0; s < 4; ++s) {
            short8 af = (s < 2)
                ? *reinterpret_cast<const short8*>(Eb + rA * ST + s * 32 + lq * 8)
                : *reinterpret_cast<const short8*>(Tb + rA * ST + (s - 2) * 32 + lq * 8);
            #pragma unroll
            for (int nt = 0; nt < 4; ++nt)
                accH[nt] = MFMA16(af, *reinterpret_cast<const short8*>(lW1 + (nt * 16 + ln) * 136 + s * 32 + lq * 8), accH[nt]);
        }
        float p0 = 0.f, p1 = 0.f, p2 = 0.f, p3 = 0.f;
        #pragma unroll
        for (int nt = 0; nt < 4; ++nt) {
            const int col = nt * 16 + ln;
            const float w2v = W2[col], bb = b1[col];
            p0 += fmaxf(accH[nt][0] + bb, 0.f) * w2v;
            p1 += fmaxf(accH[nt][1] + bb, 0.f) * w2v;
            p2 += fmaxf(accH[nt][2] + bb, 0.f) * w2v;
            p3 += fmaxf(accH[nt][3] + bb, 0.f) * w2v;
        }
        #pragma unroll
        for (int mk = 1; mk < 16; mk <<= 1) {
            p0 += __shfl_xor(p0, mk, 64);
            p1 += __shfl_xor(p1, mk, 64);
            p2 += __shfl_xor(p2, mk, 64);
            p3 += __shfl_xor(p3, mk, 64);
        }
        if (ln == 0) {
            const float b2v = b2[0];
            float pr[4] = {p0, p1, p2, p3};
            #pragma unroll
            for (int i = 0; i < 4; ++i) {
                const int m = lq * 4 + i;           // row -> (a = m&7, bl = m>>3)
                out[(long)(m & 7) * B_N + b0 + wv * 2 + (m >> 3)] = pr[i] + b2v;
            }
        }
        // no barrier: next tile's writes are to this wave's own rows; DS pipe
        // is in-order per wave, and all reads above retire before the next
        // tile's dependent MFMAs (compiler lgkmcnt) — waves free-run.
    }
}

extern "C" void kernel_launch(void* const* d_in, const int* in_sizes, int n_in,
                              void* d_out, int out_size, void* d_ws, size_t ws_size,
                              hipStream_t stream) {
    const float* states  = (const float*)d_in[0];
    const float* actions = (const float*)d_in[1];
    const float* Ws      = (const float*)d_in[2];
    const float* bs      = (const float*)d_in[3];
    const float* We      = (const float*)d_in[4];
    const float* be      = (const float*)d_in[5];
    const float* Wk      = (const float*)d_in[6];
    const float* Wsel    = (const float*)d_in[7];
    const float* Wv      = (const float*)d_in[8];
    const float* bv      = (const float*)d_in[9];
    const float* W1      = (const float*)d_in[10];
    const float* b1      = (const float*)d_in[11];
    const float* W2      = (const float*)d_in[12];
    const float* b2      = (const float*)d_in[13];
    short* wts = (short*)d_ws;
    float* out = (float*)d_out;

    prep_weights<<<(W_TOTAL + 255) / 256, 256, 0, stream>>>(Ws, We, Wk, Wsel, Wv, W1, wts);
    attention_critic_mfma<<<B_N / (TILES * 16), 512, 0, stream>>>(
        states, actions, bs, be, bv, b1, W2, b2, wts, out);
}